// Round 16
// baseline (88.586 us; speedup 1.0000x reference)
//
#include <hip/hip_runtime.h>

#define B 16384
#define C 4
#define M 512
#define D 512
#define NCH 16
#define NSEG 64   // B/256 candidate segments
#define QSCALE 16777216.0f   // 2^24 fixed-point scale for deterministic atomics

#define G_K1   64
#define G_K2   (72 * NCH)          // 1152
#define G_K4   576
#define G_BIG  (G_K1 + G_K2 + G_K4) // 1792 <= 7 blocks/CU x 256 CUs

// ---------------- BIG: k1 -> (doneA) -> k2a -> (doneR) -> k4acc ------------
// All cross-phase data written by device-scope atomics (LLC-resident; per-XCD
// L2s never hold these lines, since L2 is invalidated at launch and no block
// normal-reads a buffer before its producing handshake completes).
__global__ __launch_bounds__(256, 8) void big_fused(
    const float* __restrict__ logits,
    const float* __restrict__ ent_memo,
    const float* __restrict__ text_memo,
    const float* __restrict__ text_embeds,
    float* __restrict__ out,
    unsigned* __restrict__ doneA,
    unsigned* __restrict__ doneR,
    int* __restrict__ blockCnt,
    unsigned long long* __restrict__ candU,   // candList as u64
    int* __restrict__ rnkB,
    int* __restrict__ rnkM,
    unsigned long long* __restrict__ SQ)
{
    __shared__ __align__(16) char smem[8448];
    const int bx = blockIdx.x, tid = threadIdx.x;
    const int lane = tid & 63, wv = tid >> 6;

    if (bx < G_K1) {
        // ================= role K1: stats + candidate build ================
        int* wscan = (int*)smem;
        const int gid = bx * 256 + tid;

        float4 l = *reinterpret_cast<const float4*>(logits + (size_t)gid * 4);
        float m = l.x; int idx = 0;
        if (l.y > m) { m = l.y; idx = 1; }
        if (l.z > m) { m = l.z; idx = 2; }
        if (l.w > m) { m = l.w; idx = 3; }
        float e0 = expf(l.x - m), e1 = expf(l.y - m), e2 = expf(l.z - m), e3 = expf(l.w - m);
        float s = e0 + e1 + e2 + e3;
        float inv = 1.0f / s;
        float p0 = e0 * inv, p1 = e1 * inv, p2 = e2 * inv, p3 = e3 * inv;
        float lse = logf(s);
        float ent = -(p0 * (l.x - m - lse) + p1 * (l.y - m - lse)
                    + p2 * (l.z - m - lse) + p3 * (l.w - m - lse));
        float4 pr = { p0, p1, p2, p3 };
        *reinterpret_cast<float4*>(out + (size_t)B * 4 + (size_t)gid * 4) = pr;
        out[(size_t)B * 8 + gid] = ent;

        atomicExch(&rnkB[gid], 0);
        if (gid < C * M) { atomicExch(&rnkM[gid], 0); atomicExch(&SQ[gid], 0ULL); }

        const float* Ac = ent_memo + (idx << 9);
        bool flag = ent < Ac[M - 1];
        unsigned lo = 0;
        if (flag) {
            int l0 = 0, hi = M;                  // upper_bound -> #{A <= ent}
            while (l0 < hi) { int mid = (l0 + hi) >> 1; if (Ac[mid] <= ent) l0 = mid + 1; else hi = mid; }
            lo = (unsigned)l0;
        }
        unsigned long long mask = __ballot(flag);
        int prefix = __popcll(mask & ((1ull << lane) - 1ull));
        if (lane == 0) wscan[wv] = __popcll(mask);
        __syncthreads();
        int base = 0;
        for (int w = 0; w < wv; w++) base += wscan[w];
        if (flag) {
            unsigned meta32 = (lo << 16) | ((unsigned)idx << 14) | (unsigned)gid;
            unsigned long long entry = (unsigned long long)__float_as_uint(ent)
                                     | ((unsigned long long)meta32 << 32);
            atomicExch(&candU[bx * 256 + base + prefix], entry);
        }
        if (tid == 0)
            atomicExch(&blockCnt[bx], wscan[0] + wscan[1] + wscan[2] + wscan[3]);
        __syncthreads();                         // drain all atomics (vmcnt)
        if (tid == 0) atomicAdd(doneA, 1u);
    } else if (bx < G_K1 + G_K2) {
        // ================= role K2a: pairwise stable-rank partials =========
        uint2* ch = (uint2*)smem;
        const uint2* candList = (const uint2*)candU;
        int t0 = bx - G_K1;
        const int x = t0 % 72, y = t0 / 72;

        if (tid == 0) {
            while (atomicAdd(doneA, 0u) < (unsigned)G_K1)
                __builtin_amdgcn_s_sleep(16);
        }
        __syncthreads();

        int s0 = blockCnt[4 * y + 0];
        int s1 = blockCnt[4 * y + 1];
        int s2 = blockCnt[4 * y + 2];
        int s3 = blockCnt[4 * y + 3];
        int o1 = s0, o2 = s0 + s1, o3 = o2 + s2, total = o3 + s3;
        for (int j = tid; j < s0; j += 256) ch[j]      = candList[(4 * y + 0) * 256 + j];
        for (int j = tid; j < s1; j += 256) ch[o1 + j] = candList[(4 * y + 1) * 256 + j];
        for (int j = tid; j < s2; j += 256) ch[o2 + j] = candList[(4 * y + 2) * 256 + j];
        for (int j = tid; j < s3; j += 256) ch[o3 + j] = candList[(4 * y + 3) * 256 + j];
        __syncthreads();

        if (x < NSEG) {
            if (tid < blockCnt[x]) {
                uint2 v = candList[x * 256 + tid];
                float e = __uint_as_float(v.x);
                int lab = (int)((v.y >> 14) & 3);
                int bidx = (int)(v.y & 0x3FFF);
                int r = 0;
                for (int i = 0; i < total; i++) {
                    uint2 w = ch[i];
                    float e2 = __uint_as_float(w.x);
                    if ((int)((w.y >> 14) & 3) == lab &&
                        (e2 < e || (e2 == e && (int)(w.y & 0x3FFF) < bidx))) r++;
                }
                if (r) atomicAdd(&rnkB[x * 256 + tid], r);
            }
        } else {
            int t = (x - NSEG) * 256 + tid;       // [0, C*M)
            float Am = ent_memo[t];
            int mc = t >> 9;
            int rm = 0;
            for (int i = 0; i < total; i++) {
                uint2 w = ch[i];
                if ((int)((w.y >> 14) & 3) == mc && __uint_as_float(w.x) < Am) rm++;
            }
            if (rm) atomicAdd(&rnkM[t], rm);
        }
        __syncthreads();                         // drain atomics
        if (tid == 0) atomicAdd(doneR, 1u);
    } else {
        // ================= role K4acc: masked dense accumulate -> SQ =======
        int* meta = (int*)smem;                          // 1 KB
        float (*red)[4][64] = (float(*)[4][64])(smem + 1024);   // 4 KB
        float (*redm)[64]   = (float(*)[64])(smem + 1024);      // 1 KB (alt branch)
        const uint2* candList = (const uint2*)candU;
        const int x = bx - (G_K1 + G_K2);
        const int col0 = (x & 7) << 6;
        const int sg = wv;

        if (tid == 0) {
            while (atomicAdd(doneR, 0u) < (unsigned)G_K2)
                __builtin_amdgcn_s_sleep(16);
        }
        __syncthreads();

        if (x < 512) {
            const int seg = x >> 3;
            {
                int cnt = blockCnt[seg];
                uint2 v = candList[(seg << 8) + tid];
                int rb = rnkB[(seg << 8) + tid];
                bool kept = (tid < cnt) && ((int)(v.y >> 16) + rb < M);
                meta[tid] = kept ? (int)(((v.y >> 14) & 3) | 4u | ((v.y & 0x3FFF) << 3)) : 0;
            }
            __syncthreads();
            float a0 = 0.f, a1 = 0.f, a2 = 0.f, a3 = 0.f;
            #pragma unroll
            for (int kb = 0; kb < 8; kb++) {
                int mt0_ = meta[(((kb << 3) | 0) << 2) | sg];
                int mt1_ = meta[(((kb << 3) | 1) << 2) | sg];
                int mt2_ = meta[(((kb << 3) | 2) << 2) | sg];
                int mt3_ = meta[(((kb << 3) | 3) << 2) | sg];
                int mt4_ = meta[(((kb << 3) | 4) << 2) | sg];
                int mt5_ = meta[(((kb << 3) | 5) << 2) | sg];
                int mt6_ = meta[(((kb << 3) | 6) << 2) | sg];
                int mt7_ = meta[(((kb << 3) | 7) << 2) | sg];
                float v0_ = text_embeds[(size_t)(mt0_ >> 3) * D + col0 + lane];
                float v1_ = text_embeds[(size_t)(mt1_ >> 3) * D + col0 + lane];
                float v2_ = text_embeds[(size_t)(mt2_ >> 3) * D + col0 + lane];
                float v3_ = text_embeds[(size_t)(mt3_ >> 3) * D + col0 + lane];
                float v4_ = text_embeds[(size_t)(mt4_ >> 3) * D + col0 + lane];
                float v5_ = text_embeds[(size_t)(mt5_ >> 3) * D + col0 + lane];
                float v6_ = text_embeds[(size_t)(mt6_ >> 3) * D + col0 + lane];
                float v7_ = text_embeds[(size_t)(mt7_ >> 3) * D + col0 + lane];
                int mts[8] = { mt0_, mt1_, mt2_, mt3_, mt4_, mt5_, mt6_, mt7_ };
                float vvs[8] = { v0_, v1_, v2_, v3_, v4_, v5_, v6_, v7_ };
                #pragma unroll
                for (int u = 0; u < 8; u++) {
                    bool kept = (mts[u] & 4) != 0;
                    int lb = mts[u] & 3;
                    float vv = vvs[u];
                    a0 += (kept && lb == 0) ? vv : 0.f;
                    a1 += (kept && lb == 1) ? vv : 0.f;
                    a2 += (kept && lb == 2) ? vv : 0.f;
                    a3 += (kept && lb == 3) ? vv : 0.f;
                }
            }
            red[sg][0][lane] = a0; red[sg][1][lane] = a1;
            red[sg][2][lane] = a2; red[sg][3][lane] = a3;
            __syncthreads();
            float t = ((red[0][sg][lane] + red[1][sg][lane])
                     + red[2][sg][lane]) + red[3][sg][lane];
            long long q = llrintf(t * QSCALE);
            atomicAdd(&SQ[(sg << 9) + col0 + lane], (unsigned long long)q);
        } else {
            const int g = (x - 512) >> 3;               // rowgroup 0..7
            const int c = g >> 1;                       // label
            const int base = g << 8;
            {
                int i = base + tid;
                meta[tid] = ((i & (M - 1)) + rnkM[i] < M) ? 1 : 0;
            }
            __syncthreads();
            float a = 0.f;
            #pragma unroll
            for (int kb = 0; kb < 8; kb++) {
                float v0_ = text_memo[(size_t)(base + ((((kb << 3) | 0) << 2) | sg)) * D + col0 + lane];
                float v1_ = text_memo[(size_t)(base + ((((kb << 3) | 1) << 2) | sg)) * D + col0 + lane];
                float v2_ = text_memo[(size_t)(base + ((((kb << 3) | 2) << 2) | sg)) * D + col0 + lane];
                float v3_ = text_memo[(size_t)(base + ((((kb << 3) | 3) << 2) | sg)) * D + col0 + lane];
                float v4_ = text_memo[(size_t)(base + ((((kb << 3) | 4) << 2) | sg)) * D + col0 + lane];
                float v5_ = text_memo[(size_t)(base + ((((kb << 3) | 5) << 2) | sg)) * D + col0 + lane];
                float v6_ = text_memo[(size_t)(base + ((((kb << 3) | 6) << 2) | sg)) * D + col0 + lane];
                float v7_ = text_memo[(size_t)(base + ((((kb << 3) | 7) << 2) | sg)) * D + col0 + lane];
                a += meta[(((kb << 3) | 0) << 2) | sg] ? v0_ : 0.f;
                a += meta[(((kb << 3) | 1) << 2) | sg] ? v1_ : 0.f;
                a += meta[(((kb << 3) | 2) << 2) | sg] ? v2_ : 0.f;
                a += meta[(((kb << 3) | 3) << 2) | sg] ? v3_ : 0.f;
                a += meta[(((kb << 3) | 4) << 2) | sg] ? v4_ : 0.f;
                a += meta[(((kb << 3) | 5) << 2) | sg] ? v5_ : 0.f;
                a += meta[(((kb << 3) | 6) << 2) | sg] ? v6_ : 0.f;
                a += meta[(((kb << 3) | 7) << 2) | sg] ? v7_ : 0.f;
            }
            redm[sg][lane] = a;
            __syncthreads();
            if (tid < 64) {
                float t = ((redm[0][tid] + redm[1][tid]) + redm[2][tid]) + redm[3][tid];
                long long q = llrintf(t * QSCALE);
                atomicAdd(&SQ[(c << 9) + col0 + tid], (unsigned long long)q);
            }
        }
    }
}

// ---------------- K5: SQ->VGPR S + GEMV + combines + softmaxes -------------
__global__ __launch_bounds__(256) void k5_cosin(
    const unsigned long long* __restrict__ SQ,
    const float* __restrict__ text_embeds,
    float* __restrict__ out)
{
    const int tid = threadIdx.x;
    const int wave = tid >> 6, lane = tid & 63;
    const float sc = 1.0f / QSCALE;
    float s0[8], s1[8], s2[8], s3[8];
    #pragma unroll
    for (int j = 0; j < 8; j++) {
        s0[j] = (float)(long long)SQ[0 * 512 + lane * 8 + j] * sc;
        s1[j] = (float)(long long)SQ[1 * 512 + lane * 8 + j] * sc;
        s2[j] = (float)(long long)SQ[2 * 512 + lane * 8 + j] * sc;
        s3[j] = (float)(long long)SQ[3 * 512 + lane * 8 + j] * sc;
    }
    for (int r4 = 0; r4 < 4; r4++) {
        int b = blockIdx.x * 16 + wave * 4 + r4;
        const float4* te4 = reinterpret_cast<const float4*>(text_embeds + (size_t)b * D);
        float4 t0 = te4[lane * 2], t1 = te4[lane * 2 + 1];
        float te[8] = { t0.x, t0.y, t0.z, t0.w, t1.x, t1.y, t1.z, t1.w };
        float c0 = 0.f, c1 = 0.f, c2 = 0.f, c3 = 0.f;
        #pragma unroll
        for (int j = 0; j < 8; j++) {
            c0 += te[j] * s0[j];
            c1 += te[j] * s1[j];
            c2 += te[j] * s2[j];
            c3 += te[j] * s3[j];
        }
        for (int off = 32; off; off >>= 1) {
            c0 += __shfl_down(c0, off, 64);
            c1 += __shfl_down(c1, off, 64);
            c2 += __shfl_down(c2, off, 64);
            c3 += __shfl_down(c3, off, 64);
        }
        if (lane == 0) {
            float t0c = c0 + c2, t1c = c1 + c3;   // text_combine
            float v0c = c0 + c1, v1c = c2 + c3;   // vision_combine
            float tm = fmaxf(t0c, t1c);
            float te0 = expf(t0c - tm), te1 = expf(t1c - tm);
            float ts = te0 + te1;
            float mt0 = te0 / ts, mt1 = te1 / ts;
            float vm = fmaxf(v0c, v1c);
            float ve0 = expf(v0c - vm), ve1 = expf(v1c - vm);
            float vs = ve0 + ve1;
            float mv0 = ve0 / vs, mv1 = ve1 / vs;
            float4 o = { mt0 * mv0, mt1 * mv0, mt0 * mv1, mt1 * mv1 };
            *reinterpret_cast<float4*>(out + (size_t)b * 4) = o;
        }
    }
}

// ---------------------------------------------------------------------------
extern "C" void kernel_launch(void* const* d_in, const int* in_sizes, int n_in,
                              void* d_out, int out_size, void* d_ws, size_t ws_size,
                              hipStream_t stream)
{
    (void)in_sizes; (void)n_in; (void)out_size; (void)ws_size;
    const float* logits      = (const float*)d_in[0];
    const float* text_embeds = (const float*)d_in[1];
    const float* ent_memo    = (const float*)d_in[3];
    const float* text_memo   = (const float*)d_in[4];
    float* out = (float*)d_out;
    char* ws = (char*)d_ws;

    // workspace layout (bytes), 256-aligned
    unsigned* doneA = (unsigned*)(ws + 0);
    unsigned* doneR = (unsigned*)(ws + 128);
    int* blockCnt   = (int*)(ws + 1024);                        // 256 B
    unsigned long long* candU = (unsigned long long*)(ws + 4096);   // 128 KB -> 135168
    int* rnkB       = (int*)(ws + 135168);                      // 64 KB -> 200704
    int* rnkM       = (int*)(ws + 200704);                      // 8 KB  -> 208896
    unsigned long long* SQ = (unsigned long long*)(ws + 208896);    // 16 KB -> 225280

    hipMemsetAsync(ws, 0, 256, stream);    // zero doneA/doneR each call
    big_fused<<<G_BIG, 256, 0, stream>>>(logits, ent_memo, text_memo,
                                         text_embeds, out, doneA, doneR,
                                         blockCnt, candU, rnkB, rnkM, SQ);
    k5_cosin<<<1024, 256, 0, stream>>>(SQ, text_embeds, out);
}

// Round 17
// 47.960 us; speedup vs baseline: 1.8471x; 1.8471x over previous
//
#include <hip/hip_runtime.h>

#define B 16384
#define C 4
#define M 512
#define D 512
#define NSEG 64   // B/256 candidate segments
#define QSCALE 16777216.0f   // 2^24 fixed-point scale for deterministic atomics
#define BCAP 512             // boundary-bin capacity (expected nb ~ 15-70)

// normalize -0.0 -> +0.0 so positive-float bit ordering is valid
__device__ inline unsigned posbits(float e)
{
    unsigned b = __float_as_uint(e);
    return (b == 0x80000000u) ? 0u : b;
}
// monotone (non-strict) 8-bit bin of the entropy; ent in [0, ln4]
__device__ inline int binOfBits(unsigned bits)
{
    float e = __uint_as_float(bits);
    float s = fminf(fmaxf(e * 12000000.0f, 0.0f), 16777215.0f);
    return (int)((unsigned)s >> 16);
}

// ---------------- K1: stats + segmented candidate build --------------------
__global__ __launch_bounds__(256) void k1_stats(
    const float* __restrict__ logits,
    const float* __restrict__ ent_memo,
    float* __restrict__ out,
    int* __restrict__ blockCnt,
    uint2* __restrict__ candList,
    unsigned long long* __restrict__ SQ)
{
    __shared__ int wscan[4];
    const int tid = threadIdx.x, blk = blockIdx.x;
    const int gid = blk * 256 + tid;

    float4 l = *reinterpret_cast<const float4*>(logits + (size_t)gid * 4);
    float m = l.x; int idx = 0;
    if (l.y > m) { m = l.y; idx = 1; }
    if (l.z > m) { m = l.z; idx = 2; }
    if (l.w > m) { m = l.w; idx = 3; }
    float e0 = expf(l.x - m), e1 = expf(l.y - m), e2 = expf(l.z - m), e3 = expf(l.w - m);
    float s = e0 + e1 + e2 + e3;
    float inv = 1.0f / s;
    float p0 = e0 * inv, p1 = e1 * inv, p2 = e2 * inv, p3 = e3 * inv;
    float lse = logf(s);
    float ent = -(p0 * (l.x - m - lse) + p1 * (l.y - m - lse)
                + p2 * (l.z - m - lse) + p3 * (l.w - m - lse));
    float4 pr = { p0, p1, p2, p3 };
    *reinterpret_cast<float4*>(out + (size_t)B * 4 + (size_t)gid * 4) = pr;
    out[(size_t)B * 8 + gid] = ent;

    if (gid < C * M) SQ[gid] = 0ULL;

    float amax = ent_memo[(idx << 9) + M - 1];
    bool flag = ent < amax;
    unsigned bits = posbits(ent);

    // block-level compaction (order = b ascending within segment)
    unsigned long long mask = __ballot(flag);
    int lane = tid & 63, wv = tid >> 6;
    int prefix = __popcll(mask & ((1ull << lane) - 1ull));
    if (lane == 0) wscan[wv] = __popcll(mask);
    __syncthreads();
    int base = 0;
    for (int w = 0; w < wv; w++) base += wscan[w];
    if (flag)
        candList[blk * 256 + base + prefix] =
            make_uint2(bits, ((unsigned)idx << 14) | (unsigned)gid);
    if (tid == 0)
        blockCnt[blk] = wscan[0] + wscan[1] + wscan[2] + wscan[3];
}

// ---------------- KT: per-label threshold select (4 blocks) ----------------
// Block lab: batched-load passes (no atomic-in-loop stalls), privatized hist,
// parallel scan for boundary bin, in-block exact rank of boundary items.
__global__ __launch_bounds__(256) void kT_select(
    const int* __restrict__ blockCnt,
    const uint2* __restrict__ candList,
    const float* __restrict__ ent_memo,
    unsigned long long* __restrict__ Tkey)
{
    __shared__ int cnts[NSEG];
    __shared__ int whist[4][256];              // per-wave privatized, 4 KB
    __shared__ int cum[256];
    __shared__ unsigned long long bkeys[BCAP]; // 4 KB
    __shared__ int bnum;
    __shared__ int betaS, mremS;

    const int lab = blockIdx.x;
    const int tid = threadIdx.x;
    const int wv = tid >> 6;

    if (tid < NSEG) cnts[tid] = blockCnt[tid];
    for (int i = tid; i < 1024; i += 256) ((int*)whist)[i] = 0;
    if (tid == 0) { bnum = 0; Tkey[lab] = ~0ULL; }
    __syncthreads();

    // ---- pass 1: histogram via 8-wide batched loads ----
    for (int base = 0; base < B; base += 2048) {
        uint2 v[8];
        #pragma unroll
        for (int u = 0; u < 8; u++) v[u] = candList[base + u * 256 + tid];
        #pragma unroll
        for (int u = 0; u < 8; u++) {
            int slot = base + u * 256 + tid;
            if (tid < cnts[slot >> 8] && (int)((v[u].y >> 14) & 3) == lab)
                atomicAdd(&whist[wv][binOfBits(v[u].x)], 1);
        }
    }
    for (int i = tid; i < M; i += 256) {
        unsigned bits = posbits(ent_memo[(lab << 9) + i]);
        atomicAdd(&whist[wv][binOfBits(bits)], 1);
    }
    __syncthreads();

    // ---- parallel scan -> boundary bin beta, mrem ----
    int h = ((whist[0][tid] + whist[1][tid]) + whist[2][tid]) + whist[3][tid];
    cum[tid] = h;
    __syncthreads();
    for (int off = 1; off < 256; off <<= 1) {
        int add = (tid >= off) ? cum[tid - off] : 0;
        __syncthreads();
        cum[tid] += add;
        __syncthreads();
    }
    int cprev = tid ? cum[tid - 1] : 0;
    if (cum[tid] >= M && cprev < M) { betaS = tid; mremS = M - cprev; }
    __syncthreads();

    // ---- pass 2: collect boundary-bin items (batched loads) ----
    const int beta = betaS;
    for (int base = 0; base < B; base += 2048) {
        uint2 v[8];
        #pragma unroll
        for (int u = 0; u < 8; u++) v[u] = candList[base + u * 256 + tid];
        #pragma unroll
        for (int u = 0; u < 8; u++) {
            int slot = base + u * 256 + tid;
            if (tid < cnts[slot >> 8] && (int)((v[u].y >> 14) & 3) == lab
                && binOfBits(v[u].x) == beta) {
                int id = atomicAdd(&bnum, 1);
                if (id < BCAP)
                    bkeys[id] = ((unsigned long long)v[u].x << 15)
                              | (unsigned)(512 + (v[u].y & 0x3FFF));
            }
        }
    }
    for (int i = tid; i < M; i += 256) {
        unsigned bits = posbits(ent_memo[(lab << 9) + i]);
        if (binOfBits(bits) == beta) {
            int id = atomicAdd(&bnum, 1);
            if (id < BCAP)
                bkeys[id] = ((unsigned long long)bits << 15) | (unsigned)i;
        }
    }
    __syncthreads();

    // ---- exact rank among boundary items; winner writes Tkey ----
    int nb = bnum < BCAP ? bnum : BCAP;
    for (int t = tid; t < nb; t += 256) {
        unsigned long long k = bkeys[t];
        int r = 0;
        for (int j = 0; j < nb; j++)
            if (bkeys[j] < k) r++;
        if (r == mremS - 1) Tkey[lab] = k;     // unique (keys unique)
    }
}

// ---------------- KB: flag-masked dense accumulate -> SQ (int64 fx) --------
// blocks 0..511: batch, seg = x>>3, colchunk q = x&7 (64 cols).
// blocks 512..575: memo rowgroups. Deterministic int64 fixed-point atomics.
__global__ __launch_bounds__(256) void kB_acc(
    const int* __restrict__ blockCnt,
    const uint2* __restrict__ candList,
    const float* __restrict__ ent_memo,
    const unsigned long long* __restrict__ Tkey,
    const float* __restrict__ text_memo,
    const float* __restrict__ text_embeds,
    unsigned long long* __restrict__ SQ)
{
    __shared__ int meta[256];
    __shared__ unsigned long long TkeyS[4];
    const int x = blockIdx.x, tid = threadIdx.x;
    const int col0 = (x & 7) << 6;
    const int lane = tid & 63, sg = tid >> 6;

    if (tid < 4) TkeyS[tid] = Tkey[tid];

    if (x < 512) {
        const int seg = x >> 3;
        const int cnt = blockCnt[seg];
        uint2 v = candList[(seg << 8) + tid];
        __syncthreads();
        {
            int lab = (int)((v.y >> 14) & 3);
            unsigned long long key = ((unsigned long long)v.x << 15)
                                   | (unsigned)(512 + (v.y & 0x3FFF));
            bool kept = (tid < cnt) && (key <= TkeyS[lab]);
            meta[tid] = kept ? (int)((unsigned)lab | 4u | ((v.y & 0x3FFF) << 3)) : 0;
        }
        __syncthreads();
        float a0 = 0.f, a1 = 0.f, a2 = 0.f, a3 = 0.f;
        #pragma unroll
        for (int kb = 0; kb < 8; kb++) {
            int mts[8]; float vvs[8];
            #pragma unroll
            for (int u = 0; u < 8; u++)
                mts[u] = meta[(((kb << 3) | u) << 2) | sg];
            #pragma unroll
            for (int u = 0; u < 8; u++)
                vvs[u] = text_embeds[(size_t)(mts[u] >> 3) * D + col0 + lane];
            #pragma unroll
            for (int u = 0; u < 8; u++) {
                bool kept = (mts[u] & 4) != 0;
                int lb = mts[u] & 3;
                float vv = vvs[u];
                a0 += (kept && lb == 0) ? vv : 0.f;
                a1 += (kept && lb == 1) ? vv : 0.f;
                a2 += (kept && lb == 2) ? vv : 0.f;
                a3 += (kept && lb == 3) ? vv : 0.f;
            }
        }
        __shared__ float red[4][4][64];             // [sg][label][lane]
        red[sg][0][lane] = a0; red[sg][1][lane] = a1;
        red[sg][2][lane] = a2; red[sg][3][lane] = a3;
        __syncthreads();
        float t = ((red[0][sg][lane] + red[1][sg][lane])
                 + red[2][sg][lane]) + red[3][sg][lane];
        long long q = llrintf(t * QSCALE);
        atomicAdd(&SQ[(sg << 9) + col0 + lane], (unsigned long long)q);
    } else {
        const int g = (x - 512) >> 3;               // rowgroup 0..7
        const int c = g >> 1;                       // label
        const int base = g << 8;                    // first global memo row
        {
            int i = base + tid;
            unsigned bits = posbits(ent_memo[i]);
            unsigned long long key = ((unsigned long long)bits << 15)
                                   | (unsigned)(i & (M - 1));
            __syncthreads();
            meta[tid] = (key <= TkeyS[c]) ? 1 : 0;
        }
        __syncthreads();
        float a = 0.f;
        #pragma unroll
        for (int kb = 0; kb < 8; kb++) {
            float vvs[8];
            #pragma unroll
            for (int u = 0; u < 8; u++)
                vvs[u] = text_memo[(size_t)(base + ((((kb << 3) | u) << 2) | sg)) * D + col0 + lane];
            #pragma unroll
            for (int u = 0; u < 8; u++)
                a += meta[(((kb << 3) | u) << 2) | sg] ? vvs[u] : 0.f;
        }
        __shared__ float redm[4][64];
        redm[sg][lane] = a;
        __syncthreads();
        if (tid < 64) {
            float t = ((redm[0][tid] + redm[1][tid]) + redm[2][tid]) + redm[3][tid];
            long long q = llrintf(t * QSCALE);
            atomicAdd(&SQ[(c << 9) + col0 + tid], (unsigned long long)q);
        }
    }
}

// ---------------- KC: SQ->VGPR S + GEMV + combines + softmaxes -------------
__global__ __launch_bounds__(256) void kC_cosin(
    const unsigned long long* __restrict__ SQ,
    const float* __restrict__ text_embeds,
    float* __restrict__ out)
{
    const int tid = threadIdx.x;
    const int wave = tid >> 6, lane = tid & 63;
    const float sc = 1.0f / QSCALE;
    float s0[8], s1[8], s2[8], s3[8];
    #pragma unroll
    for (int j = 0; j < 8; j++) {
        s0[j] = (float)(long long)SQ[0 * 512 + lane * 8 + j] * sc;
        s1[j] = (float)(long long)SQ[1 * 512 + lane * 8 + j] * sc;
        s2[j] = (float)(long long)SQ[2 * 512 + lane * 8 + j] * sc;
        s3[j] = (float)(long long)SQ[3 * 512 + lane * 8 + j] * sc;
    }
    for (int r4 = 0; r4 < 4; r4++) {
        int b = blockIdx.x * 16 + wave * 4 + r4;
        const float4* te4 = reinterpret_cast<const float4*>(text_embeds + (size_t)b * D);
        float4 t0 = te4[lane * 2], t1 = te4[lane * 2 + 1];
        float te[8] = { t0.x, t0.y, t0.z, t0.w, t1.x, t1.y, t1.z, t1.w };
        float c0 = 0.f, c1 = 0.f, c2 = 0.f, c3 = 0.f;
        #pragma unroll
        for (int j = 0; j < 8; j++) {
            c0 += te[j] * s0[j];
            c1 += te[j] * s1[j];
            c2 += te[j] * s2[j];
            c3 += te[j] * s3[j];
        }
        for (int off = 32; off; off >>= 1) {
            c0 += __shfl_down(c0, off, 64);
            c1 += __shfl_down(c1, off, 64);
            c2 += __shfl_down(c2, off, 64);
            c3 += __shfl_down(c3, off, 64);
        }
        if (lane == 0) {
            float t0c = c0 + c2, t1c = c1 + c3;   // text_combine
            float v0c = c0 + c1, v1c = c2 + c3;   // vision_combine
            float tm = fmaxf(t0c, t1c);
            float te0 = expf(t0c - tm), te1 = expf(t1c - tm);
            float ts = te0 + te1;
            float mt0 = te0 / ts, mt1 = te1 / ts;
            float vm = fmaxf(v0c, v1c);
            float ve0 = expf(v0c - vm), ve1 = expf(v1c - vm);
            float vs = ve0 + ve1;
            float mv0 = ve0 / vs, mv1 = ve1 / vs;
            float4 o = { mt0 * mv0, mt1 * mv0, mt0 * mv1, mt1 * mv1 };
            *reinterpret_cast<float4*>(out + (size_t)b * 4) = o;
        }
    }
}

// ---------------------------------------------------------------------------
extern "C" void kernel_launch(void* const* d_in, const int* in_sizes, int n_in,
                              void* d_out, int out_size, void* d_ws, size_t ws_size,
                              hipStream_t stream)
{
    (void)in_sizes; (void)n_in; (void)out_size; (void)ws_size;
    const float* logits      = (const float*)d_in[0];
    const float* text_embeds = (const float*)d_in[1];
    const float* ent_memo    = (const float*)d_in[3];
    const float* text_memo   = (const float*)d_in[4];
    float* out = (float*)d_out;
    char* ws = (char*)d_ws;

    // workspace layout (bytes), 256-aligned
    int*   blockCnt = (int*)(ws + 0);                        // 256 B
    uint2* candList = (uint2*)(ws + 256);                    // 128 KB -> 131328
    unsigned long long* SQ   = (unsigned long long*)(ws + 131328); // 16 KB -> 147712
    unsigned long long* Tkey = (unsigned long long*)(ws + 147712); // 32 B

    k1_stats<<<NSEG, 256, 0, stream>>>(logits, ent_memo, out, blockCnt,
                                       candList, SQ);
    kT_select<<<C, 256, 0, stream>>>(blockCnt, candList, ent_memo, Tkey);
    kB_acc<<<576, 256, 0, stream>>>(blockCnt, candList, ent_memo, Tkey,
                                    text_memo, text_embeds, SQ);
    kC_cosin<<<1024, 256, 0, stream>>>(SQ, text_embeds, out);
}

// Round 18
// 47.936 us; speedup vs baseline: 1.8480x; 1.0005x over previous
//
#include <hip/hip_runtime.h>

#define B 16384
#define C 4
#define M 512
#define D 512
#define NSEG 64   // B/256 candidate segments
#define QSCALE 16777216.0f   // 2^24 fixed-point scale for deterministic atomics
#define BCAP 1024            // boundary-bin capacity (expected nb ~ 40-300)

// normalize -0.0 -> +0.0 so positive-float bit ordering is valid
__device__ inline unsigned posbits(float e)
{
    unsigned b = __float_as_uint(e);
    return (b == 0x80000000u) ? 0u : b;
}
// monotone (non-strict) 8-bit bin of the entropy; ent in [0, ln4]
__device__ inline int binOfBits(unsigned bits)
{
    float e = __uint_as_float(bits);
    float s = fminf(fmaxf(e * 12000000.0f, 0.0f), 16777215.0f);
    return (int)((unsigned)s >> 16);
}

// ---------------- K1: stats + candList + per-segment ushort histogram ------
__global__ __launch_bounds__(256) void k1_stats(
    const float* __restrict__ logits,
    const float* __restrict__ ent_memo,
    float* __restrict__ out,
    int* __restrict__ blockCnt,
    uint2* __restrict__ candList,
    unsigned long long* __restrict__ SQ,
    unsigned* __restrict__ hist_part)   // [NSEG][512] packed 2x ushort
{
    __shared__ int wscan[4];
    __shared__ int lh[1024];            // [lab*256+bin]
    const int tid = threadIdx.x, blk = blockIdx.x;
    const int gid = blk * 256 + tid;
    const int lane = tid & 63, wv = tid >> 6;

    for (int i = tid; i < 1024; i += 256) lh[i] = 0;

    float4 l = *reinterpret_cast<const float4*>(logits + (size_t)gid * 4);
    float m = l.x; int idx = 0;
    if (l.y > m) { m = l.y; idx = 1; }
    if (l.z > m) { m = l.z; idx = 2; }
    if (l.w > m) { m = l.w; idx = 3; }
    float e0 = expf(l.x - m), e1 = expf(l.y - m), e2 = expf(l.z - m), e3 = expf(l.w - m);
    float s = e0 + e1 + e2 + e3;
    float inv = 1.0f / s;
    float p0 = e0 * inv, p1 = e1 * inv, p2 = e2 * inv, p3 = e3 * inv;
    float lse = logf(s);
    float ent = -(p0 * (l.x - m - lse) + p1 * (l.y - m - lse)
                + p2 * (l.z - m - lse) + p3 * (l.w - m - lse));
    float4 pr = { p0, p1, p2, p3 };
    *reinterpret_cast<float4*>(out + (size_t)B * 4 + (size_t)gid * 4) = pr;
    out[(size_t)B * 8 + gid] = ent;

    if (gid < C * M) SQ[gid] = 0ULL;

    float amax = ent_memo[(idx << 9) + M - 1];
    bool flag = ent < amax;
    unsigned bits = posbits(ent);
    __syncthreads();                     // lh zeroed

    if (flag) atomicAdd(&lh[(idx << 8) | binOfBits(bits)], 1);
    if (blk < 8) {                       // memo rows ride on blocks 0..7
        unsigned mb = posbits(ent_memo[gid]);
        atomicAdd(&lh[((gid >> 9) << 8) | binOfBits(mb)], 1);
    }

    // block-level compaction (order = b ascending within segment)
    unsigned long long mask = __ballot(flag);
    int prefix = __popcll(mask & ((1ull << lane) - 1ull));
    if (lane == 0) wscan[wv] = __popcll(mask);
    __syncthreads();                     // wscan ready + lh adds done
    int base = 0;
    for (int w = 0; w < wv; w++) base += wscan[w];
    if (flag)
        candList[blk * 256 + base + prefix] =
            make_uint2(bits, ((unsigned)idx << 14) | (unsigned)gid);
    if (tid == 0)
        blockCnt[blk] = wscan[0] + wscan[1] + wscan[2] + wscan[3];

    // packed write: entry pair (2i, 2i+1) -> one uint (counts <= 256, fits)
    for (int i = tid; i < 512; i += 256)
        hist_part[blk * 512 + i] = (unsigned)lh[2 * i] | ((unsigned)lh[2 * i + 1] << 16);
}

// ---------------- KB: replicated cheap select + masked accumulate -> SQ ----
// blocks 0..511: batch, seg = x>>3, colchunk q = x&7.  512..575: memo groups.
// Select preamble is identical & deterministic in every block.
__global__ __launch_bounds__(256) void kB_acc(
    const int* __restrict__ blockCnt,
    const uint2* __restrict__ candList,
    const float* __restrict__ ent_memo,
    const unsigned* __restrict__ hist_part,
    const float* __restrict__ text_memo,
    const float* __restrict__ text_embeds,
    unsigned long long* __restrict__ SQ)
{
    __shared__ int cnts[NSEG];
    __shared__ int hist_s[1024];
    __shared__ unsigned long long bkeys[BCAP];  // 8 KB
    __shared__ int blabs[BCAP];                 // 4 KB
    __shared__ int bnum;
    __shared__ int betaS[4], mremS[4];
    __shared__ unsigned long long TkeyS[4];
    __shared__ int meta[256];

    const int x = blockIdx.x, tid = threadIdx.x;
    const int col0 = (x & 7) << 6;
    const int lane = tid & 63, sg = tid >> 6;

    // ---- phase 1: reduce hist_part (packed adds, no carry possible) ----
    if (tid < NSEG) cnts[tid] = blockCnt[tid];
    if (tid == 0) bnum = 0;
    if (tid < 4) TkeyS[tid] = ~0ULL;
    {
        unsigned a0 = 0u, a1 = 0u;
        for (int sb = 0; sb < NSEG; sb += 8) {
            unsigned v0[8], v1[8];
            #pragma unroll
            for (int u = 0; u < 8; u++) {
                v0[u] = hist_part[(sb + u) * 512 + tid];
                v1[u] = hist_part[(sb + u) * 512 + 256 + tid];
            }
            #pragma unroll
            for (int u = 0; u < 8; u++) { a0 += v0[u]; a1 += v1[u]; }
        }
        hist_s[2 * tid]           = (int)(a0 & 0xFFFFu);
        hist_s[2 * tid + 1]       = (int)(a0 >> 16);
        hist_s[512 + 2 * tid]     = (int)(a1 & 0xFFFFu);
        hist_s[512 + 2 * tid + 1] = (int)(a1 >> 16);
    }
    __syncthreads();

    // ---- phase 2: per-wave scan (wave w = label w), barrier-free ----
    if (sg < 4) {
        int b0 = hist_s[(sg << 8) | (lane * 4 + 0)];
        int b1 = hist_s[(sg << 8) | (lane * 4 + 1)];
        int b2 = hist_s[(sg << 8) | (lane * 4 + 2)];
        int b3 = hist_s[(sg << 8) | (lane * 4 + 3)];
        int loc = b0 + b1 + b2 + b3;
        int scan = loc;
        #pragma unroll
        for (int off = 1; off < 64; off <<= 1) {
            int n = __shfl_up(scan, off, 64);
            if (lane >= off) scan += n;
        }
        int excl = scan - loc;
        int c0 = excl + b0, c1 = c0 + b1, c2 = c1 + b2, c3 = c2 + b3;
        if (excl < M && c3 >= M) {          // exactly one lane per label
            int beta, mrem;
            if (c0 >= M)      { beta = lane * 4 + 0; mrem = M - excl; }
            else if (c1 >= M) { beta = lane * 4 + 1; mrem = M - c0; }
            else if (c2 >= M) { beta = lane * 4 + 2; mrem = M - c1; }
            else              { beta = lane * 4 + 3; mrem = M - c2; }
            betaS[sg] = beta; mremS[sg] = mrem;
        }
    }
    __syncthreads();

    // ---- phase 3: collect boundary-bin items (batched loads) ----
    for (int base = 0; base < B; base += 2048) {
        uint2 v[8];
        #pragma unroll
        for (int u = 0; u < 8; u++) v[u] = candList[base + u * 256 + tid];
        #pragma unroll
        for (int u = 0; u < 8; u++) {
            int slot = base + u * 256 + tid;
            int lab = (int)((v[u].y >> 14) & 3);
            if (tid < cnts[slot >> 8] && binOfBits(v[u].x) == betaS[lab]) {
                int id = atomicAdd(&bnum, 1);
                if (id < BCAP) {
                    bkeys[id] = ((unsigned long long)v[u].x << 15)
                              | (unsigned)(512 + (v[u].y & 0x3FFF));
                    blabs[id] = lab;
                }
            }
        }
    }
    for (int i = tid; i < C * M; i += 256) {
        unsigned bits = posbits(ent_memo[i]);
        int lab = i >> 9;
        if (binOfBits(bits) == betaS[lab]) {
            int id = atomicAdd(&bnum, 1);
            if (id < BCAP) {
                bkeys[id] = ((unsigned long long)bits << 15) | (unsigned)(i & (M - 1));
                blabs[id] = lab;
            }
        }
    }
    __syncthreads();

    // ---- phase 4: exact rank among boundary items -> Tkey per label ----
    {
        int nb = bnum < BCAP ? bnum : BCAP;
        for (int t = tid; t < nb; t += 256) {
            unsigned long long k = bkeys[t]; int l = blabs[t];
            int r = 0;
            for (int j = 0; j < nb; j++)
                if (blabs[j] == l && bkeys[j] < k) r++;
            if (r == mremS[l] - 1) TkeyS[l] = k;    // unique winner (keys unique)
        }
    }
    __syncthreads();

    // ---- phase 5: masked dense accumulate (proven engine) ----
    if (x < 512) {
        const int seg = x >> 3;
        const int cnt = cnts[seg];
        {
            uint2 v = candList[(seg << 8) + tid];
            int lab = (int)((v.y >> 14) & 3);
            unsigned long long key = ((unsigned long long)v.x << 15)
                                   | (unsigned)(512 + (v.y & 0x3FFF));
            bool kept = (tid < cnt) && (key <= TkeyS[lab]);
            meta[tid] = kept ? (int)((unsigned)lab | 4u | ((v.y & 0x3FFF) << 3)) : 0;
        }
        __syncthreads();
        float a0 = 0.f, a1 = 0.f, a2 = 0.f, a3 = 0.f;
        #pragma unroll
        for (int kb = 0; kb < 8; kb++) {
            int mts[8]; float vvs[8];
            #pragma unroll
            for (int u = 0; u < 8; u++)
                mts[u] = meta[(((kb << 3) | u) << 2) | sg];
            #pragma unroll
            for (int u = 0; u < 8; u++)
                vvs[u] = text_embeds[(size_t)(mts[u] >> 3) * D + col0 + lane];
            #pragma unroll
            for (int u = 0; u < 8; u++) {
                bool kept = (mts[u] & 4) != 0;
                int lb = mts[u] & 3;
                float vv = vvs[u];
                a0 += (kept && lb == 0) ? vv : 0.f;
                a1 += (kept && lb == 1) ? vv : 0.f;
                a2 += (kept && lb == 2) ? vv : 0.f;
                a3 += (kept && lb == 3) ? vv : 0.f;
            }
        }
        __shared__ float red[4][4][64];             // [sg][label][lane]
        red[sg][0][lane] = a0; red[sg][1][lane] = a1;
        red[sg][2][lane] = a2; red[sg][3][lane] = a3;
        __syncthreads();
        float t = ((red[0][sg][lane] + red[1][sg][lane])
                 + red[2][sg][lane]) + red[3][sg][lane];
        long long q = llrintf(t * QSCALE);
        atomicAdd(&SQ[(sg << 9) + col0 + lane], (unsigned long long)q);
    } else {
        const int g = (x - 512) >> 3;               // rowgroup 0..7
        const int c = g >> 1;                       // label
        const int base = g << 8;                    // first global memo row
        {
            int i = base + tid;
            unsigned bits = posbits(ent_memo[i]);
            unsigned long long key = ((unsigned long long)bits << 15)
                                   | (unsigned)(i & (M - 1));
            meta[tid] = (key <= TkeyS[c]) ? 1 : 0;
        }
        __syncthreads();
        float a = 0.f;
        #pragma unroll
        for (int kb = 0; kb < 8; kb++) {
            float vvs[8];
            #pragma unroll
            for (int u = 0; u < 8; u++)
                vvs[u] = text_memo[(size_t)(base + ((((kb << 3) | u) << 2) | sg)) * D + col0 + lane];
            #pragma unroll
            for (int u = 0; u < 8; u++)
                a += meta[(((kb << 3) | u) << 2) | sg] ? vvs[u] : 0.f;
        }
        __shared__ float redm[4][64];
        redm[sg][lane] = a;
        __syncthreads();
        if (tid < 64) {
            float t = ((redm[0][tid] + redm[1][tid]) + redm[2][tid]) + redm[3][tid];
            long long q = llrintf(t * QSCALE);
            atomicAdd(&SQ[(c << 9) + col0 + tid], (unsigned long long)q);
        }
    }
}

// ---------------- KC: SQ->VGPR S + GEMV + combines + softmaxes -------------
__global__ __launch_bounds__(256) void kC_cosin(
    const unsigned long long* __restrict__ SQ,
    const float* __restrict__ text_embeds,
    float* __restrict__ out)
{
    const int tid = threadIdx.x;
    const int wave = tid >> 6, lane = tid & 63;
    const float sc = 1.0f / QSCALE;
    float s0[8], s1[8], s2[8], s3[8];
    #pragma unroll
    for (int j = 0; j < 8; j++) {
        s0[j] = (float)(long long)SQ[0 * 512 + lane * 8 + j] * sc;
        s1[j] = (float)(long long)SQ[1 * 512 + lane * 8 + j] * sc;
        s2[j] = (float)(long long)SQ[2 * 512 + lane * 8 + j] * sc;
        s3[j] = (float)(long long)SQ[3 * 512 + lane * 8 + j] * sc;
    }
    for (int r4 = 0; r4 < 4; r4++) {
        int b = blockIdx.x * 16 + wave * 4 + r4;
        const float4* te4 = reinterpret_cast<const float4*>(text_embeds + (size_t)b * D);
        float4 t0 = te4[lane * 2], t1 = te4[lane * 2 + 1];
        float te[8] = { t0.x, t0.y, t0.z, t0.w, t1.x, t1.y, t1.z, t1.w };
        float c0 = 0.f, c1 = 0.f, c2 = 0.f, c3 = 0.f;
        #pragma unroll
        for (int j = 0; j < 8; j++) {
            c0 += te[j] * s0[j];
            c1 += te[j] * s1[j];
            c2 += te[j] * s2[j];
            c3 += te[j] * s3[j];
        }
        for (int off = 32; off; off >>= 1) {
            c0 += __shfl_down(c0, off, 64);
            c1 += __shfl_down(c1, off, 64);
            c2 += __shfl_down(c2, off, 64);
            c3 += __shfl_down(c3, off, 64);
        }
        if (lane == 0) {
            float t0c = c0 + c2, t1c = c1 + c3;   // text_combine
            float v0c = c0 + c1, v1c = c2 + c3;   // vision_combine
            float tm = fmaxf(t0c, t1c);
            float te0 = expf(t0c - tm), te1 = expf(t1c - tm);
            float ts = te0 + te1;
            float mt0 = te0 / ts, mt1 = te1 / ts;
            float vm = fmaxf(v0c, v1c);
            float ve0 = expf(v0c - vm), ve1 = expf(v1c - vm);
            float vs = ve0 + ve1;
            float mv0 = ve0 / vs, mv1 = ve1 / vs;
            float4 o = { mt0 * mv0, mt1 * mv0, mt0 * mv1, mt1 * mv1 };
            *reinterpret_cast<float4*>(out + (size_t)b * 4) = o;
        }
    }
}

// ---------------------------------------------------------------------------
extern "C" void kernel_launch(void* const* d_in, const int* in_sizes, int n_in,
                              void* d_out, int out_size, void* d_ws, size_t ws_size,
                              hipStream_t stream)
{
    (void)in_sizes; (void)n_in; (void)out_size; (void)ws_size;
    const float* logits      = (const float*)d_in[0];
    const float* text_embeds = (const float*)d_in[1];
    const float* ent_memo    = (const float*)d_in[3];
    const float* text_memo   = (const float*)d_in[4];
    float* out = (float*)d_out;
    char* ws = (char*)d_ws;

    // workspace layout (bytes), 256-aligned
    int*   blockCnt = (int*)(ws + 0);                        // 256 B
    uint2* candList = (uint2*)(ws + 256);                    // 128 KB -> 131328
    unsigned long long* SQ = (unsigned long long*)(ws + 131328); // 16 KB -> 147712
    unsigned* hist_part = (unsigned*)(ws + 147712);          // 128 KB -> 278784

    k1_stats<<<NSEG, 256, 0, stream>>>(logits, ent_memo, out, blockCnt,
                                       candList, SQ, hist_part);
    kB_acc<<<576, 256, 0, stream>>>(blockCnt, candList, ent_memo, hist_part,
                                    text_memo, text_embeds, SQ);
    kC_cosin<<<1024, 256, 0, stream>>>(SQ, text_embeds, out);
}